// Round 4
// baseline (294.649 us; speedup 1.0000x reference)
//
#include <hip/hip_runtime.h>
#include <math.h>

#define LSEQ 2048
#define KNB 64
#define BATCH 8
#define MRBF 7
#define NTILES 8192               // 2 rows per tile, 128 pairs
#define NBLOCKS 768               // 3 blocks/CU x 256 CU resident
#define BSCALE (255.0f/144.0f)

typedef __attribute__((ext_vector_type(8))) short short8;
typedef __attribute__((ext_vector_type(4))) float floatx4;

// RNE float->bf16 (cold path: weight setup)
__device__ __forceinline__ unsigned short f2bf(float f) {
    unsigned u = __float_as_uint(f);
    u += 0x7fffu + ((u >> 16) & 1u);
    return (unsigned short)(u >> 16);
}
// packed round-half-up bf16x2, 3 ops via v_perm (r4/r5/r6-proven)
__device__ __forceinline__ unsigned pkbf(float a, float b) {
    return __builtin_amdgcn_perm(__float_as_uint(b) + 0x8000u,
                                 __float_as_uint(a) + 0x8000u, 0x07060302u);
}

// ---------------------------------------------------------------------------
// 8-barrier fused kernel. Per 128-pair tile (= 2 rows): exact top-K=64
// (histogram), winners -> LDS nbrL, then the MFMA MLP with aliased LDS.
//
// LDS map (49664 B total -> 3 blocks/CU, the size proven resident in r1):
//   shorts [0,8192)      A': H1 rows 0..63   (topk scratch aliases first 4.6KB)
//   shorts [8192,16384)  B': H1 rows 64..127 / H2 rows 0..63
//   shorts [16384,24576) C : X (128x64 bf16) / H2 rows 64..127
//
// CRITICAL aliasing rule (r3 crash root cause): hist/ctrs alias H1 rows
// 2..18, whose last reader is GEMM2lo. Zeroing for the next tile therefore
// lives in the G3 phase (A' dead) and is fenced from the next pass1 by the
// loop-end barrier. Zeroing any earlier gets overwritten by G1's H1 store.
//
// Phase order per tile (8 __syncthreads):
//   pass1 | s | scan(in-reg, all waves) + pass2 | s | rank | s | xbuild | s |
//   G1 | s | G2hi | s | G2lo | s | G3+epilogue+zero-hist/ctrs | s
//
// Fragment layouts (r2/r4/r5/r6 HW-verified, absmax=0):
//  A[m][k]: m=lane&15, k=quad*8+j | B[k][n]: n=lane&15, k=quad*8+j
//  D[r][c]: r=quad*4+reg, c=lane&15
// ---------------------------------------------------------------------------
__global__ __launch_bounds__(256, 2) void fused_kernel(
    const float* __restrict__ R, const int* __restrict__ seq,
    const float* __restrict__ emb,
    const float* __restrict__ W1, const float* __restrict__ b1,
    const float* __restrict__ W2, const float* __restrict__ b2,
    const float* __restrict__ W3, const float* __restrict__ b3,
    const float* __restrict__ centers, const float* __restrict__ widths,
    float* __restrict__ out)
{
    __shared__ __align__(16) unsigned short lds[24576];   // 48 KB
    unsigned short* H1s = lds;            // shorts [0,16384)
    unsigned short* Xs  = lds + 16384;    // shorts [16384,24576)
    unsigned short* H2s = lds + 8192;     // shorts [8192,24576) (aliases H1hi+X)
    // topk scratch aliases H1 rows 0..18 (dead only after G2lo's reads):
    int*      nbrL    = (int*)lds;                     // 128 ints  [0,512)
    unsigned* hist    = (unsigned*)((char*)lds + 512); // 512 u32   [512,2560)
    float*    cand_d2 = (float*)((char*)lds + 2560);   // 2x128 f32 [2560,3584)
    int*      cand_j  = (int*)((char*)lds + 3584);     // 2x128 int [3584,4608)
    int*      tctr    = (int*)((char*)lds + 4608);     // 6 ints
    int* oPos  = tctr + 0;
    int* cCnt  = tctr + 2;
    int* fCnt  = tctr + 4;
    __shared__ float bacc[BATCH];

    const int tid  = threadIdx.x;
    const int lane = tid & 63;
    const int wv   = tid >> 6;
    const int l15  = lane & 15;
    const int q    = lane >> 4;

    // ---- persistent A-operand weight fragments (wave-sharded neurons) ----
    short8 w1f[2][2], w2f[2][4], w3f[4];
    float b1v[2][4], b2v[2][4];
    #pragma unroll
    for (int mtl = 0; mtl < 2; mtl++) {
        int m = (2*wv + mtl)*16 + l15;
        #pragma unroll
        for (int d = 0; d < 4; d++) {
            b1v[mtl][d] = b1[(2*wv + mtl)*16 + q*4 + d];
            b2v[mtl][d] = b2[(2*wv + mtl)*16 + q*4 + d];
        }
        #pragma unroll
        for (int kt = 0; kt < 2; kt++)
            #pragma unroll
            for (int jj = 0; jj < 8; jj++) {
                int k = kt*32 + q*8 + jj;
                w1f[mtl][kt][jj] = (short)((k < 48) ? f2bf(W1[k*128 + m]) : 0);
            }
        #pragma unroll
        for (int kt = 0; kt < 4; kt++)
            #pragma unroll
            for (int jj = 0; jj < 8; jj++) {
                int k = kt*32 + q*8 + jj;
                w2f[mtl][kt][jj] = (short)f2bf(W2[k*128 + m]);
            }
    }
    #pragma unroll
    for (int kt = 0; kt < 4; kt++)
        #pragma unroll
        for (int jj = 0; jj < 8; jj++) {
            int k = kt*32 + q*8 + jj;
            w3f[kt][jj] = (short)((l15 < MRBF) ? f2bf(W3[k*MRBF + l15]) : 0);
        }
    float b3C[4], cen[4], i2w[4];
    #pragma unroll
    for (int d = 0; d < 4; d++) {
        int rb = q*4 + d;
        bool ok = rb < MRBF;
        b3C[d] = ok ? b3[rb] : 0.f;
        cen[d] = ok ? centers[rb] : 0.f;
        float wd = ok ? widths[rb] : 1.f;
        i2w[d] = 0.5f / (wd*wd);
    }

    const int pl = tid >> 1, half = tid & 1;
    const int s7p = pl & 7;
    float rloc = 0.f;

    // prologue: zero scratch (bacc + hist + counters) before first pass1
    if (tid < BATCH) bacc[tid] = 0.f;
    hist[tid] = 0u; hist[tid + 256] = 0u;
    if (tid < 2) { oPos[tid] = 0; cCnt[tid] = 0; fCnt[tid] = 0; }
    __syncthreads();

    for (int tile = blockIdx.x; tile < NTILES; tile += NBLOCKS) {
        const int b     = tile >> 10;            // 1024 tiles per batch
        const int ibase = (tile & 1023) << 1;    // first row (within batch)
        const float* Rb = R + ((b << 11) * 3);

        // ===== pass1: distances -> regs, in-cutoff histogram ===========
        float px[8], py[8], pz[8];
        {
            const float4* rp = (const float4*)(Rb + tid*24);
            float4 f0=rp[0], f1=rp[1], f2=rp[2], f3=rp[3], f4=rp[4], f5=rp[5];
            px[0]=f0.x; py[0]=f0.y; pz[0]=f0.z;
            px[1]=f0.w; py[1]=f1.x; pz[1]=f1.y;
            px[2]=f1.z; py[2]=f1.w; pz[2]=f2.x;
            px[3]=f2.y; py[3]=f2.z; pz[3]=f2.w;
            px[4]=f3.x; py[4]=f3.y; pz[4]=f3.z;
            px[5]=f3.w; py[5]=f4.x; pz[5]=f4.y;
            px[6]=f4.z; py[6]=f4.w; pz[6]=f5.x;
            px[7]=f5.y; py[7]=f5.z; pz[7]=f5.w;
        }
        float cx0 = Rb[3*ibase+0], cy0 = Rb[3*ibase+1], cz0 = Rb[3*ibase+2];
        float cx1 = Rb[3*ibase+3], cy1 = Rb[3*ibase+4], cz1 = Rb[3*ibase+5];

        // bonded -> d2=1e30 (excluded from cutoff AND fill); key 0..254
        // exact-monotone in d2; beyond cutoff contributes exactly 0
        float d2r[2][8];
        #pragma unroll
        for (int u = 0; u < 8; u++) {
            int j = tid*8 + u;
            #pragma unroll
            for (int c = 0; c < 2; c++) {
                float dx = (c ? cx1 : cx0) - px[u];
                float dy = (c ? cy1 : cy0) - py[u];
                float dz = (c ? cz1 : cz0) - pz[u];
                float d2 = dx*dx + dy*dy + dz*dz;
                int dd = j - (ibase + c); dd = dd < 0 ? -dd : dd;
                if (dd <= 3) d2 = 1e30f;
                d2r[c][u] = d2;
                if (d2 < 144.0f)
                    atomicAdd(&hist[(c<<8) + (int)(d2*BSCALE)], 1u);
            }
        }
        __syncthreads();   // hist complete

        // ===== scan: redundant per-wave, results in registers ===========
        int sBr[2], sNr[2];
        #pragma unroll
        for (int c = 0; c < 2; c++) {
            uint4 hv = *(const uint4*)&hist[(c<<8) + lane*4];
            unsigned s = hv.x + hv.y + hv.z + hv.w;
            unsigned inc = s;
            #pragma unroll
            for (int off = 1; off < 64; off <<= 1) {
                unsigned n = __shfl_up(inc, off, 64);
                if (lane >= off) inc += n;
            }
            unsigned tot = __shfl(inc, 63, 64);
            if (tot < 64u) {
                sBr[c] = 255; sNr[c] = 64 - (int)tot;
            } else {
                unsigned excl = inc - s;
                bool fnd = (excl < 64u) && (64u <= inc);   // exactly one lane
                unsigned pk2 = 0u;
                if (fnd) {
                    unsigned cc = excl;
                    unsigned h4a[4] = {hv.x, hv.y, hv.z, hv.w};
                    #pragma unroll
                    for (int v = 0; v < 4; v++) {
                        if (cc < 64u && 64u <= cc + h4a[v])
                            pk2 = ((unsigned)(lane*4 + v) << 16) | (64u - cc);
                        cc += h4a[v];
                    }
                }
                unsigned long long mk = __ballot(fnd);
                int sl = __ffsll((long long)mk) - 1;
                unsigned r = __shfl(pk2, sl, 64);
                sBr[c] = (int)(r >> 16); sNr[c] = (int)(r & 0xffffu);
            }
        }

        // ===== pass2: winners -> nbrL; boundary bin -> candidates; fill ==
        #pragma unroll
        for (int u = 0; u < 8; u++) {
            int j = tid*8 + u;
            #pragma unroll
            for (int c = 0; c < 2; c++) {
                float d2 = d2r[c][u];
                int B = sBr[c];
                if (d2 < 144.0f) {
                    int key = (int)(d2*BSCALE);
                    if (key < B) {
                        int pos = atomicAdd(&oPos[c], 1);
                        nbrL[(c<<6) + pos] = j;
                    } else if (key == B) {
                        int cc = atomicAdd(&cCnt[c], 1);
                        if (cc < 128) { cand_d2[(c<<7)+cc] = d2; cand_j[(c<<7)+cc] = j; }
                    }
                } else if (B == 255 && d2 < 1e29f) {
                    // <64 inside cutoff: fill with beyond-cutoff non-bonded
                    // pairs -- each contributes exactly 0 via the smoothstep
                    int t = atomicAdd(&fCnt[c], 1);
                    if (t < sNr[c]) {
                        int pos = atomicAdd(&oPos[c], 1);
                        nbrL[(c<<6) + pos] = j;
                    }
                }
            }
        }
        __syncthreads();   // nbrL partial + cand complete

        // ===== rank: boundary bin exact (d2,j) rank; wave c -> row c =====
        if (wv < 2) {
            int B  = wv ? sBr[1] : sBr[0];
            int nd = wv ? sNr[1] : sNr[0];
            if (B != 255) {
                int cn = cCnt[wv]; if (cn > 128) cn = 128;
                for (int ci = lane; ci < cn; ci += 64) {
                    float dv = cand_d2[(wv<<7)+ci]; int jv = cand_j[(wv<<7)+ci];
                    int rank = 0;
                    for (int x = 0; x < cn; x++) {
                        float dx2 = cand_d2[(wv<<7)+x]; int jx2 = cand_j[(wv<<7)+x];
                        rank += (dx2 < dv) || (dx2 == dv && jx2 < jv);
                    }
                    if (rank < nd) {
                        int pos = atomicAdd(&oPos[wv], 1);
                        nbrL[(wv<<6) + pos] = jv;
                    }
                }
            }
        }
        __syncthreads();   // nbrL complete

        // ===== xbuild (rd nbrL, wr C) ===================================
        {
            int c  = pl >> 6;
            int bi = (b << 11) + ibase + c;
            int j  = nbrL[pl];
            int rowj = (b << 11) + j;
            int si = seq[bi], sj = seq[rowj];
            const float4* ei = (const float4*)(emb + si*16 + half*8);
            const float4* ej = (const float4*)(emb + sj*16 + half*8);
            float4 eA0 = ei[0], eA1 = ei[1], eB0 = ej[0], eB1 = ej[1];
            int rb = pl*64;
            uint4 vA = make_uint4(pkbf(eA0.x,eA0.y), pkbf(eA0.z,eA0.w),
                                  pkbf(eA1.x,eA1.y), pkbf(eA1.z,eA1.w));
            uint4 vB = make_uint4(pkbf(eB0.x,eB0.y), pkbf(eB0.z,eB0.w),
                                  pkbf(eB1.x,eB1.y), pkbf(eB1.z,eB1.w));
            uint4 vP = make_uint4(pkbf(eA0.x*eB0.x, eA0.y*eB0.y),
                                  pkbf(eA0.z*eB0.z, eA0.w*eB0.w),
                                  pkbf(eA1.x*eB1.x, eA1.y*eB1.y),
                                  pkbf(eA1.z*eB1.z, eA1.w*eB1.w));
            *(uint4*)&Xs[rb + (((0|half)^s7p)<<3)] = vA;
            *(uint4*)&Xs[rb + (((2|half)^s7p)<<3)] = vB;
            *(uint4*)&Xs[rb + (((4|half)^s7p)<<3)] = vP;
            *(uint4*)&Xs[rb + (((6|half)^s7p)<<3)] = make_uint4(0u,0u,0u,0u);
            if (!half) {
                float dx = R[bi*3+0]-R[rowj*3+0];
                float dy = R[bi*3+1]-R[rowj*3+1];
                float dz = R[bi*3+2]-R[rowj*3+2];
                rloc = sqrtf(dx*dx + dy*dy + dz*dz + 1e-12f);
            }
        }
        __syncthreads();   // X ready; nbrL dead (but A' still aliased by H1)

        // ===== GEMM1: H1 = relu(W1^T X^T + b1) [rd C, wr A'B'] ==========
        #pragma unroll
        for (int nt = 0; nt < 8; nt++) {
            int row = nt*16 + l15;
            int s7 = l15 & 7;
            const unsigned short* xr = Xs + row*64;
            short8 x0 = *(const short8*)&xr[(( q    ^ s7) << 3)];
            short8 x1 = *(const short8*)&xr[(((4|q) ^ s7) << 3)];
            #pragma unroll
            for (int mtl = 0; mtl < 2; mtl++) {
                floatx4 acc = {b1v[mtl][0], b1v[mtl][1], b1v[mtl][2], b1v[mtl][3]};
                acc = __builtin_amdgcn_mfma_f32_16x16x32_bf16(w1f[mtl][0], x0, acc, 0, 0, 0);
                acc = __builtin_amdgcn_mfma_f32_16x16x32_bf16(w1f[mtl][1], x1, acc, 0, 0, 0);
                int chnk = (((2*wv + mtl)*2 + (q>>1)) ^ s7);
                *(uint2*)&H1s[row*128 + (chnk<<3) + ((q&1)<<2)] =
                    make_uint2(pkbf(fmaxf(acc[0],0.f), fmaxf(acc[1],0.f)),
                               pkbf(fmaxf(acc[2],0.f), fmaxf(acc[3],0.f)));
            }
        }
        __syncthreads();   // H1 full; X (C region) dead

        // ===== GEMM2hi: rows 64..127 [rd B', wr C = dead X] =============
        #pragma unroll
        for (int nt = 4; nt < 8; nt++) {
            int row = nt*16 + l15;
            int s7 = l15 & 7;
            const unsigned short* hr = H1s + row*128;
            short8 hf0 = *(const short8*)&hr[(( q     ^ s7) << 3)];
            short8 hf1 = *(const short8*)&hr[((( 4|q) ^ s7) << 3)];
            short8 hf2 = *(const short8*)&hr[((( 8|q) ^ s7) << 3)];
            short8 hf3 = *(const short8*)&hr[(((12|q) ^ s7) << 3)];
            #pragma unroll
            for (int mtl = 0; mtl < 2; mtl++) {
                floatx4 acc = {b2v[mtl][0], b2v[mtl][1], b2v[mtl][2], b2v[mtl][3]};
                acc = __builtin_amdgcn_mfma_f32_16x16x32_bf16(w2f[mtl][0], hf0, acc, 0, 0, 0);
                acc = __builtin_amdgcn_mfma_f32_16x16x32_bf16(w2f[mtl][1], hf1, acc, 0, 0, 0);
                acc = __builtin_amdgcn_mfma_f32_16x16x32_bf16(w2f[mtl][2], hf2, acc, 0, 0, 0);
                acc = __builtin_amdgcn_mfma_f32_16x16x32_bf16(w2f[mtl][3], hf3, acc, 0, 0, 0);
                int chnk = (((2*wv + mtl)*2 + (q>>1)) ^ s7);
                *(uint2*)&H2s[row*128 + (chnk<<3) + ((q&1)<<2)] =
                    make_uint2(pkbf(fmaxf(acc[0],0.f), fmaxf(acc[1],0.f)),
                               pkbf(fmaxf(acc[2],0.f), fmaxf(acc[3],0.f)));
            }
        }
        __syncthreads();   // H1-hi reads done; B' region reusable

        // ===== GEMM2lo: rows 0..63 [rd A', wr B' = dead H1hi] ===========
        #pragma unroll
        for (int nt = 0; nt < 4; nt++) {
            int row = nt*16 + l15;
            int s7 = l15 & 7;
            const unsigned short* hr = H1s + row*128;
            short8 hf0 = *(const short8*)&hr[(( q     ^ s7) << 3)];
            short8 hf1 = *(const short8*)&hr[((( 4|q) ^ s7) << 3)];
            short8 hf2 = *(const short8*)&hr[((( 8|q) ^ s7) << 3)];
            short8 hf3 = *(const short8*)&hr[(((12|q) ^ s7) << 3)];
            #pragma unroll
            for (int mtl = 0; mtl < 2; mtl++) {
                floatx4 acc = {b2v[mtl][0], b2v[mtl][1], b2v[mtl][2], b2v[mtl][3]};
                acc = __builtin_amdgcn_mfma_f32_16x16x32_bf16(w2f[mtl][0], hf0, acc, 0, 0, 0);
                acc = __builtin_amdgcn_mfma_f32_16x16x32_bf16(w2f[mtl][1], hf1, acc, 0, 0, 0);
                acc = __builtin_amdgcn_mfma_f32_16x16x32_bf16(w2f[mtl][2], hf2, acc, 0, 0, 0);
                acc = __builtin_amdgcn_mfma_f32_16x16x32_bf16(w2f[mtl][3], hf3, acc, 0, 0, 0);
                int chnk = (((2*wv + mtl)*2 + (q>>1)) ^ s7);
                *(uint2*)&H2s[row*128 + (chnk<<3) + ((q&1)<<2)] =
                    make_uint2(pkbf(fmaxf(acc[0],0.f), fmaxf(acc[1],0.f)),
                               pkbf(fmaxf(acc[2],0.f), fmaxf(acc[3],0.f)));
            }
        }
        __syncthreads();   // A' (H1-lo + topk scratch region) now truly dead

        // ===== G3 phase: zero scratch for next tile + GEMM3 + epilogue ===
        // (zeroing here is safe: all A' readers done; fenced from next
        //  pass1's atomics by the loop-end barrier)
        hist[tid] = 0u; hist[tid + 256] = 0u;
        if (tid < 2) { oPos[tid] = 0; cCnt[tid] = 0; fCnt[tid] = 0; }

        float esum = 0.f;
        #pragma unroll
        for (int ntl = 0; ntl < 2; ntl++) {
            int nt = 2*wv + ntl;
            int row = nt*16 + l15;
            int s7 = l15 & 7;
            const unsigned short* hr = H2s + row*128;
            floatx4 a3 = {b3C[0], b3C[1], b3C[2], b3C[3]};
            #pragma unroll
            for (int kt = 0; kt < 4; kt++) {
                short8 hf = *(const short8*)&hr[((((kt<<2)|q) ^ s7) << 3)];
                a3 = __builtin_amdgcn_mfma_f32_16x16x32_bf16(w3f[kt], hf, a3, 0, 0, 0);
            }
            // pair p = 32wv+16ntl+l15; its r lives in lane 32ntl+2*l15
            float rr = __shfl(rloc, (ntl<<5) + 2*l15, 64);
            if (rr < 12.0f) {
                float att = 0.f;
                #pragma unroll
                for (int d = 0; d < 4; d++) {
                    if (q*4 + d < MRBF) {
                        float x = a3[d];
                        float sp = fmaxf(x, 0.f) + __logf(1.f + __expf(-fabsf(x)));
                        float df = rr - cen[d];
                        att += sp * __expf(-df*df*i2w[d]);
                    }
                }
                att += __shfl_xor(att, 16, 64);
                att += __shfl_xor(att, 32, 64);
                float tt = fminf(fmaxf((rr - 10.f)*0.5f, 0.f), 1.f);
                float sw = 1.f - tt*tt*(3.f - 2.f*tt);
                esum -= att * sw;   // 4x quad-replicated; x0.25 at flush
            }
        }
        #pragma unroll
        for (int off = 1; off < 64; off <<= 1)
            esum += __shfl_xor(esum, off, 64);
        if (lane == 0) atomicAdd(&bacc[b], esum * 0.25f);
        __syncthreads();   // zeroing + H2 reads done before next pass1
    }
    if (tid < BATCH) atomicAdd(&out[tid], bacc[tid]);
}

// ---------------------------------------------------------------------------
extern "C" void kernel_launch(void* const* d_in, const int* in_sizes, int n_in,
                              void* d_out, int out_size, void* d_ws, size_t ws_size,
                              hipStream_t stream) {
    const float* R       = (const float*)d_in[0];
    const int*   seq     = (const int*)  d_in[1];
    const float* emb     = (const float*)d_in[2];
    const float* W1      = (const float*)d_in[3];
    const float* b1      = (const float*)d_in[4];
    const float* W2      = (const float*)d_in[5];
    const float* b2      = (const float*)d_in[6];
    const float* W3      = (const float*)d_in[7];
    const float* b3      = (const float*)d_in[8];
    const float* centers = (const float*)d_in[9];
    const float* widths  = (const float*)d_in[10];
    float* out = (float*)d_out;

    hipMemsetAsync(d_out, 0, out_size * sizeof(float), stream);

    fused_kernel<<<NBLOCKS, 256, 0, stream>>>(R, seq, emb, W1, b1, W2, b2, W3, b3,
                                              centers, widths, out);
}

// Round 5
// 294.340 us; speedup vs baseline: 1.0011x; 1.0011x over previous
//
#include <hip/hip_runtime.h>
#include <math.h>

#define LSEQ 2048
#define KNB 64
#define BATCH 8
#define MRBF 7
#define NTILES 8192               // 2 rows per tile, 128 pairs
#define NBLOCKS 768               // 3 blocks/CU x 256 CU resident
#define BSCALE (255.0f/144.0f)

typedef __attribute__((ext_vector_type(8))) short short8;
typedef __attribute__((ext_vector_type(4))) float floatx4;

// RNE float->bf16 (cold path: weight setup)
__device__ __forceinline__ unsigned short f2bf(float f) {
    unsigned u = __float_as_uint(f);
    u += 0x7fffu + ((u >> 16) & 1u);
    return (unsigned short)(u >> 16);
}
// packed round-half-up bf16x2, 3 ops via v_perm (r4/r5/r6-proven)
__device__ __forceinline__ unsigned pkbf(float a, float b) {
    return __builtin_amdgcn_perm(__float_as_uint(b) + 0x8000u,
                                 __float_as_uint(a) + 0x8000u, 0x07060302u);
}

// ---------------------------------------------------------------------------
// 8-barrier fused kernel. Per 128-pair tile (= 2 rows): exact top-K=64
// (histogram), winners -> LDS nbrL, then the MFMA MLP with aliased LDS.
//
// OCCUPANCY (r0-r4 lesson): __launch_bounds__ 2nd arg sets the per-wave
// resource granule -> CP caps resident waves/EU at exactly that value.
//   (256,2): 2 blocks/CU hard cap regardless of LDS (r0/r4: occ 18-22%)
//   (256,3): 3 blocks/CU but VGPR budget ~170 -> compiler spilled (r1)
//   (256,4): VGPR budget 128 >= natural 112 -> NO spill; LDS (49664 x 3
//            <= 160K < x4) binds at 3 blocks/CU; 768 grid packs perfectly.
//
// LDS map (49664 B total -> 3 blocks/CU):
//   shorts [0,8192)      A': H1 rows 0..63   (topk scratch aliases first 4.6KB)
//   shorts [8192,16384)  B': H1 rows 64..127 / H2 rows 0..63
//   shorts [16384,24576) C : X (128x64 bf16) / H2 rows 64..127
//
// CRITICAL aliasing rule (r3 crash root cause): hist/ctrs alias H1 rows
// 2..18, whose last reader is GEMM2lo. Zeroing for the next tile therefore
// lives in the G3 phase (A' dead) and is fenced from the next pass1 by the
// loop-end barrier. Zeroing any earlier gets overwritten by G1's H1 store.
//
// Phase order per tile (8 __syncthreads):
//   pass1 | s | scan(in-reg, all waves) + pass2 | s | rank | s | xbuild | s |
//   G1 | s | G2hi | s | G2lo | s | G3+epilogue+zero-hist/ctrs | s
//
// Fragment layouts (r2/r4/r5/r6 HW-verified, absmax=0):
//  A[m][k]: m=lane&15, k=quad*8+j | B[k][n]: n=lane&15, k=quad*8+j
//  D[r][c]: r=quad*4+reg, c=lane&15
// ---------------------------------------------------------------------------
__global__ __launch_bounds__(256, 4) void fused_kernel(
    const float* __restrict__ R, const int* __restrict__ seq,
    const float* __restrict__ emb,
    const float* __restrict__ W1, const float* __restrict__ b1,
    const float* __restrict__ W2, const float* __restrict__ b2,
    const float* __restrict__ W3, const float* __restrict__ b3,
    const float* __restrict__ centers, const float* __restrict__ widths,
    float* __restrict__ out)
{
    __shared__ __align__(16) unsigned short lds[24576];   // 48 KB
    unsigned short* H1s = lds;            // shorts [0,16384)
    unsigned short* Xs  = lds + 16384;    // shorts [16384,24576)
    unsigned short* H2s = lds + 8192;     // shorts [8192,24576) (aliases H1hi+X)
    // topk scratch aliases H1 rows 0..18 (dead only after G2lo's reads):
    int*      nbrL    = (int*)lds;                     // 128 ints  [0,512)
    unsigned* hist    = (unsigned*)((char*)lds + 512); // 512 u32   [512,2560)
    float*    cand_d2 = (float*)((char*)lds + 2560);   // 2x128 f32 [2560,3584)
    int*      cand_j  = (int*)((char*)lds + 3584);     // 2x128 int [3584,4608)
    int*      tctr    = (int*)((char*)lds + 4608);     // 6 ints
    int* oPos  = tctr + 0;
    int* cCnt  = tctr + 2;
    int* fCnt  = tctr + 4;
    __shared__ float bacc[BATCH];

    const int tid  = threadIdx.x;
    const int lane = tid & 63;
    const int wv   = tid >> 6;
    const int l15  = lane & 15;
    const int q    = lane >> 4;

    // ---- persistent A-operand weight fragments (wave-sharded neurons) ----
    short8 w1f[2][2], w2f[2][4], w3f[4];
    float b1v[2][4], b2v[2][4];
    #pragma unroll
    for (int mtl = 0; mtl < 2; mtl++) {
        int m = (2*wv + mtl)*16 + l15;
        #pragma unroll
        for (int d = 0; d < 4; d++) {
            b1v[mtl][d] = b1[(2*wv + mtl)*16 + q*4 + d];
            b2v[mtl][d] = b2[(2*wv + mtl)*16 + q*4 + d];
        }
        #pragma unroll
        for (int kt = 0; kt < 2; kt++)
            #pragma unroll
            for (int jj = 0; jj < 8; jj++) {
                int k = kt*32 + q*8 + jj;
                w1f[mtl][kt][jj] = (short)((k < 48) ? f2bf(W1[k*128 + m]) : 0);
            }
        #pragma unroll
        for (int kt = 0; kt < 4; kt++)
            #pragma unroll
            for (int jj = 0; jj < 8; jj++) {
                int k = kt*32 + q*8 + jj;
                w2f[mtl][kt][jj] = (short)f2bf(W2[k*128 + m]);
            }
    }
    #pragma unroll
    for (int kt = 0; kt < 4; kt++)
        #pragma unroll
        for (int jj = 0; jj < 8; jj++) {
            int k = kt*32 + q*8 + jj;
            w3f[kt][jj] = (short)((l15 < MRBF) ? f2bf(W3[k*MRBF + l15]) : 0);
        }
    float b3C[4], cen[4], i2w[4];
    #pragma unroll
    for (int d = 0; d < 4; d++) {
        int rb = q*4 + d;
        bool ok = rb < MRBF;
        b3C[d] = ok ? b3[rb] : 0.f;
        cen[d] = ok ? centers[rb] : 0.f;
        float wd = ok ? widths[rb] : 1.f;
        i2w[d] = 0.5f / (wd*wd);
    }

    const int pl = tid >> 1, half = tid & 1;
    const int s7p = pl & 7;
    float rloc = 0.f;

    // prologue: zero scratch (bacc + hist + counters) before first pass1
    if (tid < BATCH) bacc[tid] = 0.f;
    hist[tid] = 0u; hist[tid + 256] = 0u;
    if (tid < 2) { oPos[tid] = 0; cCnt[tid] = 0; fCnt[tid] = 0; }
    __syncthreads();

    for (int tile = blockIdx.x; tile < NTILES; tile += NBLOCKS) {
        const int b     = tile >> 10;            // 1024 tiles per batch
        const int ibase = (tile & 1023) << 1;    // first row (within batch)
        const float* Rb = R + ((b << 11) * 3);

        // ===== pass1: distances -> regs, in-cutoff histogram ===========
        float px[8], py[8], pz[8];
        {
            const float4* rp = (const float4*)(Rb + tid*24);
            float4 f0=rp[0], f1=rp[1], f2=rp[2], f3=rp[3], f4=rp[4], f5=rp[5];
            px[0]=f0.x; py[0]=f0.y; pz[0]=f0.z;
            px[1]=f0.w; py[1]=f1.x; pz[1]=f1.y;
            px[2]=f1.z; py[2]=f1.w; pz[2]=f2.x;
            px[3]=f2.y; py[3]=f2.z; pz[3]=f2.w;
            px[4]=f3.x; py[4]=f3.y; pz[4]=f3.z;
            px[5]=f3.w; py[5]=f4.x; pz[5]=f4.y;
            px[6]=f4.z; py[6]=f4.w; pz[6]=f5.x;
            px[7]=f5.y; py[7]=f5.z; pz[7]=f5.w;
        }
        float cx0 = Rb[3*ibase+0], cy0 = Rb[3*ibase+1], cz0 = Rb[3*ibase+2];
        float cx1 = Rb[3*ibase+3], cy1 = Rb[3*ibase+4], cz1 = Rb[3*ibase+5];

        // bonded -> d2=1e30 (excluded from cutoff AND fill); key 0..254
        // exact-monotone in d2; beyond cutoff contributes exactly 0
        float d2r[2][8];
        #pragma unroll
        for (int u = 0; u < 8; u++) {
            int j = tid*8 + u;
            #pragma unroll
            for (int c = 0; c < 2; c++) {
                float dx = (c ? cx1 : cx0) - px[u];
                float dy = (c ? cy1 : cy0) - py[u];
                float dz = (c ? cz1 : cz0) - pz[u];
                float d2 = dx*dx + dy*dy + dz*dz;
                int dd = j - (ibase + c); dd = dd < 0 ? -dd : dd;
                if (dd <= 3) d2 = 1e30f;
                d2r[c][u] = d2;
                if (d2 < 144.0f)
                    atomicAdd(&hist[(c<<8) + (int)(d2*BSCALE)], 1u);
            }
        }
        __syncthreads();   // hist complete

        // ===== scan: redundant per-wave, results in registers ===========
        int sBr[2], sNr[2];
        #pragma unroll
        for (int c = 0; c < 2; c++) {
            uint4 hv = *(const uint4*)&hist[(c<<8) + lane*4];
            unsigned s = hv.x + hv.y + hv.z + hv.w;
            unsigned inc = s;
            #pragma unroll
            for (int off = 1; off < 64; off <<= 1) {
                unsigned n = __shfl_up(inc, off, 64);
                if (lane >= off) inc += n;
            }
            unsigned tot = __shfl(inc, 63, 64);
            if (tot < 64u) {
                sBr[c] = 255; sNr[c] = 64 - (int)tot;
            } else {
                unsigned excl = inc - s;
                bool fnd = (excl < 64u) && (64u <= inc);   // exactly one lane
                unsigned pk2 = 0u;
                if (fnd) {
                    unsigned cc = excl;
                    unsigned h4a[4] = {hv.x, hv.y, hv.z, hv.w};
                    #pragma unroll
                    for (int v = 0; v < 4; v++) {
                        if (cc < 64u && 64u <= cc + h4a[v])
                            pk2 = ((unsigned)(lane*4 + v) << 16) | (64u - cc);
                        cc += h4a[v];
                    }
                }
                unsigned long long mk = __ballot(fnd);
                int sl = __ffsll((long long)mk) - 1;
                unsigned r = __shfl(pk2, sl, 64);
                sBr[c] = (int)(r >> 16); sNr[c] = (int)(r & 0xffffu);
            }
        }

        // ===== pass2: winners -> nbrL; boundary bin -> candidates; fill ==
        #pragma unroll
        for (int u = 0; u < 8; u++) {
            int j = tid*8 + u;
            #pragma unroll
            for (int c = 0; c < 2; c++) {
                float d2 = d2r[c][u];
                int B = sBr[c];
                if (d2 < 144.0f) {
                    int key = (int)(d2*BSCALE);
                    if (key < B) {
                        int pos = atomicAdd(&oPos[c], 1);
                        nbrL[(c<<6) + pos] = j;
                    } else if (key == B) {
                        int cc = atomicAdd(&cCnt[c], 1);
                        if (cc < 128) { cand_d2[(c<<7)+cc] = d2; cand_j[(c<<7)+cc] = j; }
                    }
                } else if (B == 255 && d2 < 1e29f) {
                    // <64 inside cutoff: fill with beyond-cutoff non-bonded
                    // pairs -- each contributes exactly 0 via the smoothstep
                    int t = atomicAdd(&fCnt[c], 1);
                    if (t < sNr[c]) {
                        int pos = atomicAdd(&oPos[c], 1);
                        nbrL[(c<<6) + pos] = j;
                    }
                }
            }
        }
        __syncthreads();   // nbrL partial + cand complete

        // ===== rank: boundary bin exact (d2,j) rank; wave c -> row c =====
        if (wv < 2) {
            int B  = wv ? sBr[1] : sBr[0];
            int nd = wv ? sNr[1] : sNr[0];
            if (B != 255) {
                int cn = cCnt[wv]; if (cn > 128) cn = 128;
                for (int ci = lane; ci < cn; ci += 64) {
                    float dv = cand_d2[(wv<<7)+ci]; int jv = cand_j[(wv<<7)+ci];
                    int rank = 0;
                    for (int x = 0; x < cn; x++) {
                        float dx2 = cand_d2[(wv<<7)+x]; int jx2 = cand_j[(wv<<7)+x];
                        rank += (dx2 < dv) || (dx2 == dv && jx2 < jv);
                    }
                    if (rank < nd) {
                        int pos = atomicAdd(&oPos[wv], 1);
                        nbrL[(wv<<6) + pos] = jv;
                    }
                }
            }
        }
        __syncthreads();   // nbrL complete

        // ===== xbuild (rd nbrL, wr C) ===================================
        {
            int c  = pl >> 6;
            int bi = (b << 11) + ibase + c;
            int j  = nbrL[pl];
            int rowj = (b << 11) + j;
            int si = seq[bi], sj = seq[rowj];
            const float4* ei = (const float4*)(emb + si*16 + half*8);
            const float4* ej = (const float4*)(emb + sj*16 + half*8);
            float4 eA0 = ei[0], eA1 = ei[1], eB0 = ej[0], eB1 = ej[1];
            int rb = pl*64;
            uint4 vA = make_uint4(pkbf(eA0.x,eA0.y), pkbf(eA0.z,eA0.w),
                                  pkbf(eA1.x,eA1.y), pkbf(eA1.z,eA1.w));
            uint4 vB = make_uint4(pkbf(eB0.x,eB0.y), pkbf(eB0.z,eB0.w),
                                  pkbf(eB1.x,eB1.y), pkbf(eB1.z,eB1.w));
            uint4 vP = make_uint4(pkbf(eA0.x*eB0.x, eA0.y*eB0.y),
                                  pkbf(eA0.z*eB0.z, eA0.w*eB0.w),
                                  pkbf(eA1.x*eB1.x, eA1.y*eB1.y),
                                  pkbf(eA1.z*eB1.z, eA1.w*eB1.w));
            *(uint4*)&Xs[rb + (((0|half)^s7p)<<3)] = vA;
            *(uint4*)&Xs[rb + (((2|half)^s7p)<<3)] = vB;
            *(uint4*)&Xs[rb + (((4|half)^s7p)<<3)] = vP;
            *(uint4*)&Xs[rb + (((6|half)^s7p)<<3)] = make_uint4(0u,0u,0u,0u);
            if (!half) {
                float dx = R[bi*3+0]-R[rowj*3+0];
                float dy = R[bi*3+1]-R[rowj*3+1];
                float dz = R[bi*3+2]-R[rowj*3+2];
                rloc = sqrtf(dx*dx + dy*dy + dz*dz + 1e-12f);
            }
        }
        __syncthreads();   // X ready; nbrL dead (but A' still aliased by H1)

        // ===== GEMM1: H1 = relu(W1^T X^T + b1) [rd C, wr A'B'] ==========
        #pragma unroll
        for (int nt = 0; nt < 8; nt++) {
            int row = nt*16 + l15;
            int s7 = l15 & 7;
            const unsigned short* xr = Xs + row*64;
            short8 x0 = *(const short8*)&xr[(( q    ^ s7) << 3)];
            short8 x1 = *(const short8*)&xr[(((4|q) ^ s7) << 3)];
            #pragma unroll
            for (int mtl = 0; mtl < 2; mtl++) {
                floatx4 acc = {b1v[mtl][0], b1v[mtl][1], b1v[mtl][2], b1v[mtl][3]};
                acc = __builtin_amdgcn_mfma_f32_16x16x32_bf16(w1f[mtl][0], x0, acc, 0, 0, 0);
                acc = __builtin_amdgcn_mfma_f32_16x16x32_bf16(w1f[mtl][1], x1, acc, 0, 0, 0);
                int chnk = (((2*wv + mtl)*2 + (q>>1)) ^ s7);
                *(uint2*)&H1s[row*128 + (chnk<<3) + ((q&1)<<2)] =
                    make_uint2(pkbf(fmaxf(acc[0],0.f), fmaxf(acc[1],0.f)),
                               pkbf(fmaxf(acc[2],0.f), fmaxf(acc[3],0.f)));
            }
        }
        __syncthreads();   // H1 full; X (C region) dead

        // ===== GEMM2hi: rows 64..127 [rd B', wr C = dead X] =============
        #pragma unroll
        for (int nt = 4; nt < 8; nt++) {
            int row = nt*16 + l15;
            int s7 = l15 & 7;
            const unsigned short* hr = H1s + row*128;
            short8 hf0 = *(const short8*)&hr[(( q     ^ s7) << 3)];
            short8 hf1 = *(const short8*)&hr[((( 4|q) ^ s7) << 3)];
            short8 hf2 = *(const short8*)&hr[((( 8|q) ^ s7) << 3)];
            short8 hf3 = *(const short8*)&hr[(((12|q) ^ s7) << 3)];
            #pragma unroll
            for (int mtl = 0; mtl < 2; mtl++) {
                floatx4 acc = {b2v[mtl][0], b2v[mtl][1], b2v[mtl][2], b2v[mtl][3]};
                acc = __builtin_amdgcn_mfma_f32_16x16x32_bf16(w2f[mtl][0], hf0, acc, 0, 0, 0);
                acc = __builtin_amdgcn_mfma_f32_16x16x32_bf16(w2f[mtl][1], hf1, acc, 0, 0, 0);
                acc = __builtin_amdgcn_mfma_f32_16x16x32_bf16(w2f[mtl][2], hf2, acc, 0, 0, 0);
                acc = __builtin_amdgcn_mfma_f32_16x16x32_bf16(w2f[mtl][3], hf3, acc, 0, 0, 0);
                int chnk = (((2*wv + mtl)*2 + (q>>1)) ^ s7);
                *(uint2*)&H2s[row*128 + (chnk<<3) + ((q&1)<<2)] =
                    make_uint2(pkbf(fmaxf(acc[0],0.f), fmaxf(acc[1],0.f)),
                               pkbf(fmaxf(acc[2],0.f), fmaxf(acc[3],0.f)));
            }
        }
        __syncthreads();   // H1-hi reads done; B' region reusable

        // ===== GEMM2lo: rows 0..63 [rd A', wr B' = dead H1hi] ===========
        #pragma unroll
        for (int nt = 0; nt < 4; nt++) {
            int row = nt*16 + l15;
            int s7 = l15 & 7;
            const unsigned short* hr = H1s + row*128;
            short8 hf0 = *(const short8*)&hr[(( q     ^ s7) << 3)];
            short8 hf1 = *(const short8*)&hr[((( 4|q) ^ s7) << 3)];
            short8 hf2 = *(const short8*)&hr[((( 8|q) ^ s7) << 3)];
            short8 hf3 = *(const short8*)&hr[(((12|q) ^ s7) << 3)];
            #pragma unroll
            for (int mtl = 0; mtl < 2; mtl++) {
                floatx4 acc = {b2v[mtl][0], b2v[mtl][1], b2v[mtl][2], b2v[mtl][3]};
                acc = __builtin_amdgcn_mfma_f32_16x16x32_bf16(w2f[mtl][0], hf0, acc, 0, 0, 0);
                acc = __builtin_amdgcn_mfma_f32_16x16x32_bf16(w2f[mtl][1], hf1, acc, 0, 0, 0);
                acc = __builtin_amdgcn_mfma_f32_16x16x32_bf16(w2f[mtl][2], hf2, acc, 0, 0, 0);
                acc = __builtin_amdgcn_mfma_f32_16x16x32_bf16(w2f[mtl][3], hf3, acc, 0, 0, 0);
                int chnk = (((2*wv + mtl)*2 + (q>>1)) ^ s7);
                *(uint2*)&H2s[row*128 + (chnk<<3) + ((q&1)<<2)] =
                    make_uint2(pkbf(fmaxf(acc[0],0.f), fmaxf(acc[1],0.f)),
                               pkbf(fmaxf(acc[2],0.f), fmaxf(acc[3],0.f)));
            }
        }
        __syncthreads();   // A' (H1-lo + topk scratch region) now truly dead

        // ===== G3 phase: zero scratch for next tile + GEMM3 + epilogue ===
        // (zeroing here is safe: all A' readers done; fenced from next
        //  pass1's atomics by the loop-end barrier)
        hist[tid] = 0u; hist[tid + 256] = 0u;
        if (tid < 2) { oPos[tid] = 0; cCnt[tid] = 0; fCnt[tid] = 0; }

        float esum = 0.f;
        #pragma unroll
        for (int ntl = 0; ntl < 2; ntl++) {
            int nt = 2*wv + ntl;
            int row = nt*16 + l15;
            int s7 = l15 & 7;
            const unsigned short* hr = H2s + row*128;
            floatx4 a3 = {b3C[0], b3C[1], b3C[2], b3C[3]};
            #pragma unroll
            for (int kt = 0; kt < 4; kt++) {
                short8 hf = *(const short8*)&hr[((((kt<<2)|q) ^ s7) << 3)];
                a3 = __builtin_amdgcn_mfma_f32_16x16x32_bf16(w3f[kt], hf, a3, 0, 0, 0);
            }
            // pair p = 32wv+16ntl+l15; its r lives in lane 32ntl+2*l15
            float rr = __shfl(rloc, (ntl<<5) + 2*l15, 64);
            if (rr < 12.0f) {
                float att = 0.f;
                #pragma unroll
                for (int d = 0; d < 4; d++) {
                    if (q*4 + d < MRBF) {
                        float x = a3[d];
                        float sp = fmaxf(x, 0.f) + __logf(1.f + __expf(-fabsf(x)));
                        float df = rr - cen[d];
                        att += sp * __expf(-df*df*i2w[d]);
                    }
                }
                att += __shfl_xor(att, 16, 64);
                att += __shfl_xor(att, 32, 64);
                float tt = fminf(fmaxf((rr - 10.f)*0.5f, 0.f), 1.f);
                float sw = 1.f - tt*tt*(3.f - 2.f*tt);
                esum -= att * sw;   // 4x quad-replicated; x0.25 at flush
            }
        }
        #pragma unroll
        for (int off = 1; off < 64; off <<= 1)
            esum += __shfl_xor(esum, off, 64);
        if (lane == 0) atomicAdd(&bacc[b], esum * 0.25f);
        __syncthreads();   // zeroing + H2 reads done before next pass1
    }
    if (tid < BATCH) atomicAdd(&out[tid], bacc[tid]);
}

// ---------------------------------------------------------------------------
extern "C" void kernel_launch(void* const* d_in, const int* in_sizes, int n_in,
                              void* d_out, int out_size, void* d_ws, size_t ws_size,
                              hipStream_t stream) {
    const float* R       = (const float*)d_in[0];
    const int*   seq     = (const int*)  d_in[1];
    const float* emb     = (const float*)d_in[2];
    const float* W1      = (const float*)d_in[3];
    const float* b1      = (const float*)d_in[4];
    const float* W2      = (const float*)d_in[5];
    const float* b2      = (const float*)d_in[6];
    const float* W3      = (const float*)d_in[7];
    const float* b3      = (const float*)d_in[8];
    const float* centers = (const float*)d_in[9];
    const float* widths  = (const float*)d_in[10];
    float* out = (float*)d_out;

    hipMemsetAsync(d_out, 0, out_size * sizeof(float), stream);

    fused_kernel<<<NBLOCKS, 256, 0, stream>>>(R, seq, emb, W1, b1, W2, b2, W3, b3,
                                              centers, widths, out);
}

// Round 6
// 255.644 us; speedup vs baseline: 1.1526x; 1.1514x over previous
//
#include <hip/hip_runtime.h>
#include <math.h>

#define LSEQ 2048
#define KNB 64
#define BATCH 8
#define MRBF 7
#define NTILES 8192               // 2 rows per tile, 128 pairs
#define NBLOCKS 512               // 2 blocks/CU x 256 CU -- exact packing (r5 lesson)
#define BSCALE (255.0f/144.0f)

typedef __attribute__((ext_vector_type(8))) short short8;
typedef __attribute__((ext_vector_type(4))) float floatx4;

// RNE float->bf16 (cold path: weight setup)
__device__ __forceinline__ unsigned short f2bf(float f) {
    unsigned u = __float_as_uint(f);
    u += 0x7fffu + ((u >> 16) & 1u);
    return (unsigned short)(u >> 16);
}
// packed round-half-up bf16x2, 3 ops via v_perm (r4/r5/r6-proven)
__device__ __forceinline__ unsigned pkbf(float a, float b) {
    return __builtin_amdgcn_perm(__float_as_uint(b) + 0x8000u,
                                 __float_as_uint(a) + 0x8000u, 0x07060302u);
}

// ---------------------------------------------------------------------------
// 7-barrier fused kernel. Per 128-pair tile (= 2 rows): exact top-K=64
// (histogram), winners -> LDS nbrL, then the MFMA MLP.
//
// RESIDENCY (r0-r5 lessons): this kernel runs at 2 blocks/CU in every clean
// config (48KB or 64KB LDS, LB(256,2) or (256,4)); 3/CU was only ever seen
// with spill. So: NBLOCKS=512 for exact packing (768 on 2 slots cost +33%
// pure imbalance, r4/r5), and use the roomy 64KB LDS map since 3-block
// residency is unreachable anyway -- buys a single-phase GEMM2 (one fewer
// barrier than the 48KB aliased map).
//
// LDS map (66048 B total):
//   shorts [0,16384)     H1 (topk scratch aliases first 4.6KB; zeroed in G3)
//   shorts [16384,24576) X (128x64 bf16), dead after GEMM1
//   shorts [16384,32768) H2 (aliases X)
//
// Phase order per tile (7 __syncthreads):
//   pass1 | s | scan(in-reg, all waves) + pass2 | s | rank | s | xbuild | s |
//   G1 | s | G2 | s | G3+epilogue+zero-hist/ctrs | s
// Aliasing audit: hist/ctrs alias H1 rows 2..18, last read by G2 -> zeroing
// lives in G3 phase, fenced from next pass1 by the loop-end barrier (r3
// crash lesson). X dead after G1 -> G2 writes H2 over it, fenced by s5.
//
// Fragment layouts (r2/r4/r5/r6 HW-verified, absmax=0):
//  A[m][k]: m=lane&15, k=quad*8+j | B[k][n]: n=lane&15, k=quad*8+j
//  D[r][c]: r=quad*4+reg, c=lane&15
// ---------------------------------------------------------------------------
__global__ __launch_bounds__(256, 2) void fused_kernel(
    const float* __restrict__ R, const int* __restrict__ seq,
    const float* __restrict__ emb,
    const float* __restrict__ W1, const float* __restrict__ b1,
    const float* __restrict__ W2, const float* __restrict__ b2,
    const float* __restrict__ W3, const float* __restrict__ b3,
    const float* __restrict__ centers, const float* __restrict__ widths,
    float* __restrict__ out)
{
    __shared__ __align__(16) unsigned short lds[32768];   // 64 KB
    unsigned short* H1s = lds;            // shorts [0,16384)
    unsigned short* Xs  = lds + 16384;    // shorts [16384,24576)
    unsigned short* H2s = lds + 16384;    // shorts [16384,32768) (aliases X)
    // topk scratch aliases H1 rows 0..18 (dead only after G2's reads):
    int*      nbrL    = (int*)lds;                     // 128 ints  [0,512)
    unsigned* hist    = (unsigned*)((char*)lds + 512); // 512 u32   [512,2560)
    float*    cand_d2 = (float*)((char*)lds + 2560);   // 2x128 f32 [2560,3584)
    int*      cand_j  = (int*)((char*)lds + 3584);     // 2x128 int [3584,4608)
    int*      tctr    = (int*)((char*)lds + 4608);     // 6 ints
    int* oPos  = tctr + 0;
    int* cCnt  = tctr + 2;
    int* fCnt  = tctr + 4;
    __shared__ float bacc[BATCH];

    const int tid  = threadIdx.x;
    const int lane = tid & 63;
    const int wv   = tid >> 6;
    const int l15  = lane & 15;
    const int q    = lane >> 4;

    // ---- persistent A-operand weight fragments (wave-sharded neurons) ----
    short8 w1f[2][2], w2f[2][4], w3f[4];
    float b1v[2][4], b2v[2][4];
    #pragma unroll
    for (int mtl = 0; mtl < 2; mtl++) {
        int m = (2*wv + mtl)*16 + l15;
        #pragma unroll
        for (int d = 0; d < 4; d++) {
            b1v[mtl][d] = b1[(2*wv + mtl)*16 + q*4 + d];
            b2v[mtl][d] = b2[(2*wv + mtl)*16 + q*4 + d];
        }
        #pragma unroll
        for (int kt = 0; kt < 2; kt++)
            #pragma unroll
            for (int jj = 0; jj < 8; jj++) {
                int k = kt*32 + q*8 + jj;
                w1f[mtl][kt][jj] = (short)((k < 48) ? f2bf(W1[k*128 + m]) : 0);
            }
        #pragma unroll
        for (int kt = 0; kt < 4; kt++)
            #pragma unroll
            for (int jj = 0; jj < 8; jj++) {
                int k = kt*32 + q*8 + jj;
                w2f[mtl][kt][jj] = (short)f2bf(W2[k*128 + m]);
            }
    }
    #pragma unroll
    for (int kt = 0; kt < 4; kt++)
        #pragma unroll
        for (int jj = 0; jj < 8; jj++) {
            int k = kt*32 + q*8 + jj;
            w3f[kt][jj] = (short)((l15 < MRBF) ? f2bf(W3[k*MRBF + l15]) : 0);
        }
    float b3C[4], cen[4], i2w[4];
    #pragma unroll
    for (int d = 0; d < 4; d++) {
        int rb = q*4 + d;
        bool ok = rb < MRBF;
        b3C[d] = ok ? b3[rb] : 0.f;
        cen[d] = ok ? centers[rb] : 0.f;
        float wd = ok ? widths[rb] : 1.f;
        i2w[d] = 0.5f / (wd*wd);
    }

    const int pl = tid >> 1, half = tid & 1;
    const int s7p = pl & 7;
    float rloc = 0.f;

    // prologue: zero scratch (bacc + hist + counters) before first pass1
    if (tid < BATCH) bacc[tid] = 0.f;
    hist[tid] = 0u; hist[tid + 256] = 0u;
    if (tid < 2) { oPos[tid] = 0; cCnt[tid] = 0; fCnt[tid] = 0; }
    __syncthreads();

    for (int tile = blockIdx.x; tile < NTILES; tile += NBLOCKS) {
        const int b     = tile >> 10;            // 1024 tiles per batch
        const int ibase = (tile & 1023) << 1;    // first row (within batch)
        const float* Rb = R + ((b << 11) * 3);

        // ===== pass1: distances -> regs, in-cutoff histogram ===========
        float px[8], py[8], pz[8];
        {
            const float4* rp = (const float4*)(Rb + tid*24);
            float4 f0=rp[0], f1=rp[1], f2=rp[2], f3=rp[3], f4=rp[4], f5=rp[5];
            px[0]=f0.x; py[0]=f0.y; pz[0]=f0.z;
            px[1]=f0.w; py[1]=f1.x; pz[1]=f1.y;
            px[2]=f1.z; py[2]=f1.w; pz[2]=f2.x;
            px[3]=f2.y; py[3]=f2.z; pz[3]=f2.w;
            px[4]=f3.x; py[4]=f3.y; pz[4]=f3.z;
            px[5]=f3.w; py[5]=f4.x; pz[5]=f4.y;
            px[6]=f4.z; py[6]=f4.w; pz[6]=f5.x;
            px[7]=f5.y; py[7]=f5.z; pz[7]=f5.w;
        }
        float cx0 = Rb[3*ibase+0], cy0 = Rb[3*ibase+1], cz0 = Rb[3*ibase+2];
        float cx1 = Rb[3*ibase+3], cy1 = Rb[3*ibase+4], cz1 = Rb[3*ibase+5];

        // bonded -> d2=1e30 (excluded from cutoff AND fill); key 0..254
        // exact-monotone in d2; beyond cutoff contributes exactly 0
        float d2r[2][8];
        #pragma unroll
        for (int u = 0; u < 8; u++) {
            int j = tid*8 + u;
            #pragma unroll
            for (int c = 0; c < 2; c++) {
                float dx = (c ? cx1 : cx0) - px[u];
                float dy = (c ? cy1 : cy0) - py[u];
                float dz = (c ? cz1 : cz0) - pz[u];
                float d2 = dx*dx + dy*dy + dz*dz;
                int dd = j - (ibase + c); dd = dd < 0 ? -dd : dd;
                if (dd <= 3) d2 = 1e30f;
                d2r[c][u] = d2;
                if (d2 < 144.0f)
                    atomicAdd(&hist[(c<<8) + (int)(d2*BSCALE)], 1u);
            }
        }
        __syncthreads();   // hist complete

        // ===== scan: redundant per-wave, results in registers ===========
        int sBr[2], sNr[2];
        #pragma unroll
        for (int c = 0; c < 2; c++) {
            uint4 hv = *(const uint4*)&hist[(c<<8) + lane*4];
            unsigned s = hv.x + hv.y + hv.z + hv.w;
            unsigned inc = s;
            #pragma unroll
            for (int off = 1; off < 64; off <<= 1) {
                unsigned n = __shfl_up(inc, off, 64);
                if (lane >= off) inc += n;
            }
            unsigned tot = __shfl(inc, 63, 64);
            if (tot < 64u) {
                sBr[c] = 255; sNr[c] = 64 - (int)tot;
            } else {
                unsigned excl = inc - s;
                bool fnd = (excl < 64u) && (64u <= inc);   // exactly one lane
                unsigned pk2 = 0u;
                if (fnd) {
                    unsigned cc = excl;
                    unsigned h4a[4] = {hv.x, hv.y, hv.z, hv.w};
                    #pragma unroll
                    for (int v = 0; v < 4; v++) {
                        if (cc < 64u && 64u <= cc + h4a[v])
                            pk2 = ((unsigned)(lane*4 + v) << 16) | (64u - cc);
                        cc += h4a[v];
                    }
                }
                unsigned long long mk = __ballot(fnd);
                int sl = __ffsll((long long)mk) - 1;
                unsigned r = __shfl(pk2, sl, 64);
                sBr[c] = (int)(r >> 16); sNr[c] = (int)(r & 0xffffu);
            }
        }

        // ===== pass2: winners -> nbrL; boundary bin -> candidates; fill ==
        #pragma unroll
        for (int u = 0; u < 8; u++) {
            int j = tid*8 + u;
            #pragma unroll
            for (int c = 0; c < 2; c++) {
                float d2 = d2r[c][u];
                int B = sBr[c];
                if (d2 < 144.0f) {
                    int key = (int)(d2*BSCALE);
                    if (key < B) {
                        int pos = atomicAdd(&oPos[c], 1);
                        nbrL[(c<<6) + pos] = j;
                    } else if (key == B) {
                        int cc = atomicAdd(&cCnt[c], 1);
                        if (cc < 128) { cand_d2[(c<<7)+cc] = d2; cand_j[(c<<7)+cc] = j; }
                    }
                } else if (B == 255 && d2 < 1e29f) {
                    // <64 inside cutoff: fill with beyond-cutoff non-bonded
                    // pairs -- each contributes exactly 0 via the smoothstep
                    int t = atomicAdd(&fCnt[c], 1);
                    if (t < sNr[c]) {
                        int pos = atomicAdd(&oPos[c], 1);
                        nbrL[(c<<6) + pos] = j;
                    }
                }
            }
        }
        __syncthreads();   // nbrL partial + cand complete

        // ===== rank: boundary bin exact (d2,j) rank; wave c -> row c =====
        if (wv < 2) {
            int B  = wv ? sBr[1] : sBr[0];
            int nd = wv ? sNr[1] : sNr[0];
            if (B != 255) {
                int cn = cCnt[wv]; if (cn > 128) cn = 128;
                for (int ci = lane; ci < cn; ci += 64) {
                    float dv = cand_d2[(wv<<7)+ci]; int jv = cand_j[(wv<<7)+ci];
                    int rank = 0;
                    for (int x = 0; x < cn; x++) {
                        float dx2 = cand_d2[(wv<<7)+x]; int jx2 = cand_j[(wv<<7)+x];
                        rank += (dx2 < dv) || (dx2 == dv && jx2 < jv);
                    }
                    if (rank < nd) {
                        int pos = atomicAdd(&oPos[wv], 1);
                        nbrL[(wv<<6) + pos] = jv;
                    }
                }
            }
        }
        __syncthreads();   // nbrL complete

        // ===== xbuild (rd nbrL, wr X) ===================================
        {
            int c  = pl >> 6;
            int bi = (b << 11) + ibase + c;
            int j  = nbrL[pl];
            int rowj = (b << 11) + j;
            int si = seq[bi], sj = seq[rowj];
            const float4* ei = (const float4*)(emb + si*16 + half*8);
            const float4* ej = (const float4*)(emb + sj*16 + half*8);
            float4 eA0 = ei[0], eA1 = ei[1], eB0 = ej[0], eB1 = ej[1];
            int rb = pl*64;
            uint4 vA = make_uint4(pkbf(eA0.x,eA0.y), pkbf(eA0.z,eA0.w),
                                  pkbf(eA1.x,eA1.y), pkbf(eA1.z,eA1.w));
            uint4 vB = make_uint4(pkbf(eB0.x,eB0.y), pkbf(eB0.z,eB0.w),
                                  pkbf(eB1.x,eB1.y), pkbf(eB1.z,eB1.w));
            uint4 vP = make_uint4(pkbf(eA0.x*eB0.x, eA0.y*eB0.y),
                                  pkbf(eA0.z*eB0.z, eA0.w*eB0.w),
                                  pkbf(eA1.x*eB1.x, eA1.y*eB1.y),
                                  pkbf(eA1.z*eB1.z, eA1.w*eB1.w));
            *(uint4*)&Xs[rb + (((0|half)^s7p)<<3)] = vA;
            *(uint4*)&Xs[rb + (((2|half)^s7p)<<3)] = vB;
            *(uint4*)&Xs[rb + (((4|half)^s7p)<<3)] = vP;
            *(uint4*)&Xs[rb + (((6|half)^s7p)<<3)] = make_uint4(0u,0u,0u,0u);
            if (!half) {
                float dx = R[bi*3+0]-R[rowj*3+0];
                float dy = R[bi*3+1]-R[rowj*3+1];
                float dz = R[bi*3+2]-R[rowj*3+2];
                rloc = sqrtf(dx*dx + dy*dy + dz*dz + 1e-12f);
            }
        }
        __syncthreads();   // X ready; nbrL dead (but region still aliased by H1)

        // ===== GEMM1: H1 = relu(W1^T X^T + b1) [rd X, wr H1] ============
        #pragma unroll
        for (int nt = 0; nt < 8; nt++) {
            int row = nt*16 + l15;
            int s7 = l15 & 7;
            const unsigned short* xr = Xs + row*64;
            short8 x0 = *(const short8*)&xr[(( q    ^ s7) << 3)];
            short8 x1 = *(const short8*)&xr[(((4|q) ^ s7) << 3)];
            #pragma unroll
            for (int mtl = 0; mtl < 2; mtl++) {
                floatx4 acc = {b1v[mtl][0], b1v[mtl][1], b1v[mtl][2], b1v[mtl][3]};
                acc = __builtin_amdgcn_mfma_f32_16x16x32_bf16(w1f[mtl][0], x0, acc, 0, 0, 0);
                acc = __builtin_amdgcn_mfma_f32_16x16x32_bf16(w1f[mtl][1], x1, acc, 0, 0, 0);
                int chnk = (((2*wv + mtl)*2 + (q>>1)) ^ s7);
                *(uint2*)&H1s[row*128 + (chnk<<3) + ((q&1)<<2)] =
                    make_uint2(pkbf(fmaxf(acc[0],0.f), fmaxf(acc[1],0.f)),
                               pkbf(fmaxf(acc[2],0.f), fmaxf(acc[3],0.f)));
            }
        }
        __syncthreads();   // H1 full; X dead

        // ===== GEMM2: H2 = relu(W2^T H1^T + b2) [rd H1, wr H2 = dead X] ==
        #pragma unroll
        for (int nt = 0; nt < 8; nt++) {
            int row = nt*16 + l15;
            int s7 = l15 & 7;
            const unsigned short* hr = H1s + row*128;
            short8 hf0 = *(const short8*)&hr[(( q     ^ s7) << 3)];
            short8 hf1 = *(const short8*)&hr[((( 4|q) ^ s7) << 3)];
            short8 hf2 = *(const short8*)&hr[((( 8|q) ^ s7) << 3)];
            short8 hf3 = *(const short8*)&hr[(((12|q) ^ s7) << 3)];
            #pragma unroll
            for (int mtl = 0; mtl < 2; mtl++) {
                floatx4 acc = {b2v[mtl][0], b2v[mtl][1], b2v[mtl][2], b2v[mtl][3]};
                acc = __builtin_amdgcn_mfma_f32_16x16x32_bf16(w2f[mtl][0], hf0, acc, 0, 0, 0);
                acc = __builtin_amdgcn_mfma_f32_16x16x32_bf16(w2f[mtl][1], hf1, acc, 0, 0, 0);
                acc = __builtin_amdgcn_mfma_f32_16x16x32_bf16(w2f[mtl][2], hf2, acc, 0, 0, 0);
                acc = __builtin_amdgcn_mfma_f32_16x16x32_bf16(w2f[mtl][3], hf3, acc, 0, 0, 0);
                int chnk = (((2*wv + mtl)*2 + (q>>1)) ^ s7);
                *(uint2*)&H2s[row*128 + (chnk<<3) + ((q&1)<<2)] =
                    make_uint2(pkbf(fmaxf(acc[0],0.f), fmaxf(acc[1],0.f)),
                               pkbf(fmaxf(acc[2],0.f), fmaxf(acc[3],0.f)));
            }
        }
        __syncthreads();   // H2 full; H1 + topk scratch region dead

        // ===== G3 phase: zero scratch for next tile + GEMM3 + epilogue ===
        // (zeroing here is safe: all H1 readers done; fenced from next
        //  pass1's atomics by the loop-end barrier)
        hist[tid] = 0u; hist[tid + 256] = 0u;
        if (tid < 2) { oPos[tid] = 0; cCnt[tid] = 0; fCnt[tid] = 0; }

        float esum = 0.f;
        #pragma unroll
        for (int ntl = 0; ntl < 2; ntl++) {
            int nt = 2*wv + ntl;
            int row = nt*16 + l15;
            int s7 = l15 & 7;
            const unsigned short* hr = H2s + row*128;
            floatx4 a3 = {b3C[0], b3C[1], b3C[2], b3C[3]};
            #pragma unroll
            for (int kt = 0; kt < 4; kt++) {
                short8 hf = *(const short8*)&hr[((((kt<<2)|q) ^ s7) << 3)];
                a3 = __builtin_amdgcn_mfma_f32_16x16x32_bf16(w3f[kt], hf, a3, 0, 0, 0);
            }
            // pair p = 32wv+16ntl+l15; its r lives in lane 32ntl+2*l15
            float rr = __shfl(rloc, (ntl<<5) + 2*l15, 64);
            if (rr < 12.0f) {
                float att = 0.f;
                #pragma unroll
                for (int d = 0; d < 4; d++) {
                    if (q*4 + d < MRBF) {
                        float x = a3[d];
                        float sp = fmaxf(x, 0.f) + __logf(1.f + __expf(-fabsf(x)));
                        float df = rr - cen[d];
                        att += sp * __expf(-df*df*i2w[d]);
                    }
                }
                att += __shfl_xor(att, 16, 64);
                att += __shfl_xor(att, 32, 64);
                float tt = fminf(fmaxf((rr - 10.f)*0.5f, 0.f), 1.f);
                float sw = 1.f - tt*tt*(3.f - 2.f*tt);
                esum -= att * sw;   // 4x quad-replicated; x0.25 at flush
            }
        }
        #pragma unroll
        for (int off = 1; off < 64; off <<= 1)
            esum += __shfl_xor(esum, off, 64);
        if (lane == 0) atomicAdd(&bacc[b], esum * 0.25f);
        __syncthreads();   // zeroing + H2 reads done before next pass1
    }
    if (tid < BATCH) atomicAdd(&out[tid], bacc[tid]);
}

// ---------------------------------------------------------------------------
extern "C" void kernel_launch(void* const* d_in, const int* in_sizes, int n_in,
                              void* d_out, int out_size, void* d_ws, size_t ws_size,
                              hipStream_t stream) {
    const float* R       = (const float*)d_in[0];
    const int*   seq     = (const int*)  d_in[1];
    const float* emb     = (const float*)d_in[2];
    const float* W1      = (const float*)d_in[3];
    const float* b1      = (const float*)d_in[4];
    const float* W2      = (const float*)d_in[5];
    const float* b2      = (const float*)d_in[6];
    const float* W3      = (const float*)d_in[7];
    const float* b3      = (const float*)d_in[8];
    const float* centers = (const float*)d_in[9];
    const float* widths  = (const float*)d_in[10];
    float* out = (float*)d_out;

    hipMemsetAsync(d_out, 0, out_size * sizeof(float), stream);

    fused_kernel<<<NBLOCKS, 256, 0, stream>>>(R, seq, emb, W1, b1, W2, b2, W3, b3,
                                              centers, widths, out);
}

// Round 7
// 246.071 us; speedup vs baseline: 1.1974x; 1.0389x over previous
//
#include <hip/hip_runtime.h>
#include <math.h>

#define LSEQ 2048
#define KNB 64
#define BATCH 8
#define MRBF 7
#define NTILES 8192               // 2 rows per tile, 128 pairs
#define NBLOCKS 768               // 3 blocks/CU x 256 CU resident (if granted)
#define BSCALE (255.0f/144.0f)

typedef __attribute__((ext_vector_type(8))) short short8;
typedef __attribute__((ext_vector_type(4))) float floatx4;

// RNE float->bf16 (cold path: weight setup)
__device__ __forceinline__ unsigned short f2bf(float f) {
    unsigned u = __float_as_uint(f);
    u += 0x7fffu + ((u >> 16) & 1u);
    return (unsigned short)(u >> 16);
}
// packed round-half-up bf16x2, 3 ops via v_perm (r4/r5/r6-proven)
__device__ __forceinline__ unsigned pkbf(float a, float b) {
    return __builtin_amdgcn_perm(__float_as_uint(b) + 0x8000u,
                                 __float_as_uint(a) + 0x8000u, 0x07060302u);
}

// ---------------------------------------------------------------------------
// 8-barrier fused kernel. Per 128-pair tile (= 2 rows): exact top-K=64
// (histogram), winners -> LDS nbrL, then the MFMA MLP with aliased LDS.
//
// RESIDENCY MATRIX (r0-r6): CP grants 3 blocks/CU ONLY when launch_bounds
// 2nd arg == 3 (r1: occ 33%). (256,2) and (256,4) both pin at 2 blocks/CU
// even when LDS fits 3 (r4/r5/r6). r1's spill came from its fat pipelined
// body (needed >170 VGPR); THIS lean body compiles at 112-116 VGPR, under
// the 3-wave/EU budget -> (256,3) with no spill. LDS 49664 x 3 = 148992
// <= 163840. NBLOCKS=768 = 3 x 256 exact packing.
//
// LDS map (49664 B total):
//   shorts [0,8192)      A': H1 rows 0..63   (topk scratch aliases first 4.6KB)
//   shorts [8192,16384)  B': H1 rows 64..127 / H2 rows 0..63
//   shorts [16384,24576) C : X (128x64 bf16) / H2 rows 64..127
//
// CRITICAL aliasing rule (r3 crash root cause): hist/ctrs alias H1 rows
// 2..18, whose last reader is GEMM2lo. Zeroing for the next tile therefore
// lives in the G3 phase (A' dead) and is fenced from the next pass1 by the
// loop-end barrier. Zeroing any earlier gets overwritten by G1's H1 store.
//
// Phase order per tile (8 __syncthreads):
//   pass1 | s | scan(in-reg, all waves) + pass2 | s | rank | s | xbuild | s |
//   G1 | s | G2hi | s | G2lo | s | G3+epilogue+zero-hist/ctrs | s
//
// Fragment layouts (r2/r4/r5/r6 HW-verified, absmax=0):
//  A[m][k]: m=lane&15, k=quad*8+j | B[k][n]: n=lane&15, k=quad*8+j
//  D[r][c]: r=quad*4+reg, c=lane&15
// ---------------------------------------------------------------------------
__global__ __launch_bounds__(256, 3) void fused_kernel(
    const float* __restrict__ R, const int* __restrict__ seq,
    const float* __restrict__ emb,
    const float* __restrict__ W1, const float* __restrict__ b1,
    const float* __restrict__ W2, const float* __restrict__ b2,
    const float* __restrict__ W3, const float* __restrict__ b3,
    const float* __restrict__ centers, const float* __restrict__ widths,
    float* __restrict__ out)
{
    __shared__ __align__(16) unsigned short lds[24576];   // 48 KB
    unsigned short* H1s = lds;            // shorts [0,16384)
    unsigned short* Xs  = lds + 16384;    // shorts [16384,24576)
    unsigned short* H2s = lds + 8192;     // shorts [8192,24576) (aliases H1hi+X)
    // topk scratch aliases H1 rows 0..18 (dead only after G2lo's reads):
    int*      nbrL    = (int*)lds;                     // 128 ints  [0,512)
    unsigned* hist    = (unsigned*)((char*)lds + 512); // 512 u32   [512,2560)
    float*    cand_d2 = (float*)((char*)lds + 2560);   // 2x128 f32 [2560,3584)
    int*      cand_j  = (int*)((char*)lds + 3584);     // 2x128 int [3584,4608)
    int*      tctr    = (int*)((char*)lds + 4608);     // 6 ints
    int* oPos  = tctr + 0;
    int* cCnt  = tctr + 2;
    int* fCnt  = tctr + 4;
    __shared__ float bacc[BATCH];

    const int tid  = threadIdx.x;
    const int lane = tid & 63;
    const int wv   = tid >> 6;
    const int l15  = lane & 15;
    const int q    = lane >> 4;

    // ---- persistent A-operand weight fragments (wave-sharded neurons) ----
    short8 w1f[2][2], w2f[2][4], w3f[4];
    float b1v[2][4], b2v[2][4];
    #pragma unroll
    for (int mtl = 0; mtl < 2; mtl++) {
        int m = (2*wv + mtl)*16 + l15;
        #pragma unroll
        for (int d = 0; d < 4; d++) {
            b1v[mtl][d] = b1[(2*wv + mtl)*16 + q*4 + d];
            b2v[mtl][d] = b2[(2*wv + mtl)*16 + q*4 + d];
        }
        #pragma unroll
        for (int kt = 0; kt < 2; kt++)
            #pragma unroll
            for (int jj = 0; jj < 8; jj++) {
                int k = kt*32 + q*8 + jj;
                w1f[mtl][kt][jj] = (short)((k < 48) ? f2bf(W1[k*128 + m]) : 0);
            }
        #pragma unroll
        for (int kt = 0; kt < 4; kt++)
            #pragma unroll
            for (int jj = 0; jj < 8; jj++) {
                int k = kt*32 + q*8 + jj;
                w2f[mtl][kt][jj] = (short)f2bf(W2[k*128 + m]);
            }
    }
    #pragma unroll
    for (int kt = 0; kt < 4; kt++)
        #pragma unroll
        for (int jj = 0; jj < 8; jj++) {
            int k = kt*32 + q*8 + jj;
            w3f[kt][jj] = (short)((l15 < MRBF) ? f2bf(W3[k*MRBF + l15]) : 0);
        }
    float b3C[4], cen[4], i2w[4];
    #pragma unroll
    for (int d = 0; d < 4; d++) {
        int rb = q*4 + d;
        bool ok = rb < MRBF;
        b3C[d] = ok ? b3[rb] : 0.f;
        cen[d] = ok ? centers[rb] : 0.f;
        float wd = ok ? widths[rb] : 1.f;
        i2w[d] = 0.5f / (wd*wd);
    }

    const int pl = tid >> 1, half = tid & 1;
    const int s7p = pl & 7;
    float rloc = 0.f;

    // prologue: zero scratch (bacc + hist + counters) before first pass1
    if (tid < BATCH) bacc[tid] = 0.f;
    hist[tid] = 0u; hist[tid + 256] = 0u;
    if (tid < 2) { oPos[tid] = 0; cCnt[tid] = 0; fCnt[tid] = 0; }
    __syncthreads();

    for (int tile = blockIdx.x; tile < NTILES; tile += NBLOCKS) {
        const int b     = tile >> 10;            // 1024 tiles per batch
        const int ibase = (tile & 1023) << 1;    // first row (within batch)
        const float* Rb = R + ((b << 11) * 3);

        // ===== pass1: distances -> regs, in-cutoff histogram ===========
        float px[8], py[8], pz[8];
        {
            const float4* rp = (const float4*)(Rb + tid*24);
            float4 f0=rp[0], f1=rp[1], f2=rp[2], f3=rp[3], f4=rp[4], f5=rp[5];
            px[0]=f0.x; py[0]=f0.y; pz[0]=f0.z;
            px[1]=f0.w; py[1]=f1.x; pz[1]=f1.y;
            px[2]=f1.z; py[2]=f1.w; pz[2]=f2.x;
            px[3]=f2.y; py[3]=f2.z; pz[3]=f2.w;
            px[4]=f3.x; py[4]=f3.y; pz[4]=f3.z;
            px[5]=f3.w; py[5]=f4.x; pz[5]=f4.y;
            px[6]=f4.z; py[6]=f4.w; pz[6]=f5.x;
            px[7]=f5.y; py[7]=f5.z; pz[7]=f5.w;
        }
        float cx0 = Rb[3*ibase+0], cy0 = Rb[3*ibase+1], cz0 = Rb[3*ibase+2];
        float cx1 = Rb[3*ibase+3], cy1 = Rb[3*ibase+4], cz1 = Rb[3*ibase+5];

        // bonded -> d2=1e30 (excluded from cutoff AND fill); key 0..254
        // exact-monotone in d2; beyond cutoff contributes exactly 0
        float d2r[2][8];
        #pragma unroll
        for (int u = 0; u < 8; u++) {
            int j = tid*8 + u;
            #pragma unroll
            for (int c = 0; c < 2; c++) {
                float dx = (c ? cx1 : cx0) - px[u];
                float dy = (c ? cy1 : cy0) - py[u];
                float dz = (c ? cz1 : cz0) - pz[u];
                float d2 = dx*dx + dy*dy + dz*dz;
                int dd = j - (ibase + c); dd = dd < 0 ? -dd : dd;
                if (dd <= 3) d2 = 1e30f;
                d2r[c][u] = d2;
                if (d2 < 144.0f)
                    atomicAdd(&hist[(c<<8) + (int)(d2*BSCALE)], 1u);
            }
        }
        __syncthreads();   // hist complete

        // ===== scan: redundant per-wave, results in registers ===========
        int sBr[2], sNr[2];
        #pragma unroll
        for (int c = 0; c < 2; c++) {
            uint4 hv = *(const uint4*)&hist[(c<<8) + lane*4];
            unsigned s = hv.x + hv.y + hv.z + hv.w;
            unsigned inc = s;
            #pragma unroll
            for (int off = 1; off < 64; off <<= 1) {
                unsigned n = __shfl_up(inc, off, 64);
                if (lane >= off) inc += n;
            }
            unsigned tot = __shfl(inc, 63, 64);
            if (tot < 64u) {
                sBr[c] = 255; sNr[c] = 64 - (int)tot;
            } else {
                unsigned excl = inc - s;
                bool fnd = (excl < 64u) && (64u <= inc);   // exactly one lane
                unsigned pk2 = 0u;
                if (fnd) {
                    unsigned cc = excl;
                    unsigned h4a[4] = {hv.x, hv.y, hv.z, hv.w};
                    #pragma unroll
                    for (int v = 0; v < 4; v++) {
                        if (cc < 64u && 64u <= cc + h4a[v])
                            pk2 = ((unsigned)(lane*4 + v) << 16) | (64u - cc);
                        cc += h4a[v];
                    }
                }
                unsigned long long mk = __ballot(fnd);
                int sl = __ffsll((long long)mk) - 1;
                unsigned r = __shfl(pk2, sl, 64);
                sBr[c] = (int)(r >> 16); sNr[c] = (int)(r & 0xffffu);
            }
        }

        // ===== pass2: winners -> nbrL; boundary bin -> candidates; fill ==
        #pragma unroll
        for (int u = 0; u < 8; u++) {
            int j = tid*8 + u;
            #pragma unroll
            for (int c = 0; c < 2; c++) {
                float d2 = d2r[c][u];
                int B = sBr[c];
                if (d2 < 144.0f) {
                    int key = (int)(d2*BSCALE);
                    if (key < B) {
                        int pos = atomicAdd(&oPos[c], 1);
                        nbrL[(c<<6) + pos] = j;
                    } else if (key == B) {
                        int cc = atomicAdd(&cCnt[c], 1);
                        if (cc < 128) { cand_d2[(c<<7)+cc] = d2; cand_j[(c<<7)+cc] = j; }
                    }
                } else if (B == 255 && d2 < 1e29f) {
                    // <64 inside cutoff: fill with beyond-cutoff non-bonded
                    // pairs -- each contributes exactly 0 via the smoothstep
                    int t = atomicAdd(&fCnt[c], 1);
                    if (t < sNr[c]) {
                        int pos = atomicAdd(&oPos[c], 1);
                        nbrL[(c<<6) + pos] = j;
                    }
                }
            }
        }
        __syncthreads();   // nbrL partial + cand complete

        // ===== rank: boundary bin exact (d2,j) rank; wave c -> row c =====
        if (wv < 2) {
            int B  = wv ? sBr[1] : sBr[0];
            int nd = wv ? sNr[1] : sNr[0];
            if (B != 255) {
                int cn = cCnt[wv]; if (cn > 128) cn = 128;
                for (int ci = lane; ci < cn; ci += 64) {
                    float dv = cand_d2[(wv<<7)+ci]; int jv = cand_j[(wv<<7)+ci];
                    int rank = 0;
                    for (int x = 0; x < cn; x++) {
                        float dx2 = cand_d2[(wv<<7)+x]; int jx2 = cand_j[(wv<<7)+x];
                        rank += (dx2 < dv) || (dx2 == dv && jx2 < jv);
                    }
                    if (rank < nd) {
                        int pos = atomicAdd(&oPos[wv], 1);
                        nbrL[(wv<<6) + pos] = jv;
                    }
                }
            }
        }
        __syncthreads();   // nbrL complete

        // ===== xbuild (rd nbrL, wr C) ===================================
        {
            int c  = pl >> 6;
            int bi = (b << 11) + ibase + c;
            int j  = nbrL[pl];
            int rowj = (b << 11) + j;
            int si = seq[bi], sj = seq[rowj];
            const float4* ei = (const float4*)(emb + si*16 + half*8);
            const float4* ej = (const float4*)(emb + sj*16 + half*8);
            float4 eA0 = ei[0], eA1 = ei[1], eB0 = ej[0], eB1 = ej[1];
            int rb = pl*64;
            uint4 vA = make_uint4(pkbf(eA0.x,eA0.y), pkbf(eA0.z,eA0.w),
                                  pkbf(eA1.x,eA1.y), pkbf(eA1.z,eA1.w));
            uint4 vB = make_uint4(pkbf(eB0.x,eB0.y), pkbf(eB0.z,eB0.w),
                                  pkbf(eB1.x,eB1.y), pkbf(eB1.z,eB1.w));
            uint4 vP = make_uint4(pkbf(eA0.x*eB0.x, eA0.y*eB0.y),
                                  pkbf(eA0.z*eB0.z, eA0.w*eB0.w),
                                  pkbf(eA1.x*eB1.x, eA1.y*eB1.y),
                                  pkbf(eA1.z*eB1.z, eA1.w*eB1.w));
            *(uint4*)&Xs[rb + (((0|half)^s7p)<<3)] = vA;
            *(uint4*)&Xs[rb + (((2|half)^s7p)<<3)] = vB;
            *(uint4*)&Xs[rb + (((4|half)^s7p)<<3)] = vP;
            *(uint4*)&Xs[rb + (((6|half)^s7p)<<3)] = make_uint4(0u,0u,0u,0u);
            if (!half) {
                float dx = R[bi*3+0]-R[rowj*3+0];
                float dy = R[bi*3+1]-R[rowj*3+1];
                float dz = R[bi*3+2]-R[rowj*3+2];
                rloc = sqrtf(dx*dx + dy*dy + dz*dz + 1e-12f);
            }
        }
        __syncthreads();   // X ready; nbrL dead (but A' still aliased by H1)

        // ===== GEMM1: H1 = relu(W1^T X^T + b1) [rd C, wr A'B'] ==========
        #pragma unroll
        for (int nt = 0; nt < 8; nt++) {
            int row = nt*16 + l15;
            int s7 = l15 & 7;
            const unsigned short* xr = Xs + row*64;
            short8 x0 = *(const short8*)&xr[(( q    ^ s7) << 3)];
            short8 x1 = *(const short8*)&xr[(((4|q) ^ s7) << 3)];
            #pragma unroll
            for (int mtl = 0; mtl < 2; mtl++) {
                floatx4 acc = {b1v[mtl][0], b1v[mtl][1], b1v[mtl][2], b1v[mtl][3]};
                acc = __builtin_amdgcn_mfma_f32_16x16x32_bf16(w1f[mtl][0], x0, acc, 0, 0, 0);
                acc = __builtin_amdgcn_mfma_f32_16x16x32_bf16(w1f[mtl][1], x1, acc, 0, 0, 0);
                int chnk = (((2*wv + mtl)*2 + (q>>1)) ^ s7);
                *(uint2*)&H1s[row*128 + (chnk<<3) + ((q&1)<<2)] =
                    make_uint2(pkbf(fmaxf(acc[0],0.f), fmaxf(acc[1],0.f)),
                               pkbf(fmaxf(acc[2],0.f), fmaxf(acc[3],0.f)));
            }
        }
        __syncthreads();   // H1 full; X (C region) dead

        // ===== GEMM2hi: rows 64..127 [rd B', wr C = dead X] =============
        #pragma unroll
        for (int nt = 4; nt < 8; nt++) {
            int row = nt*16 + l15;
            int s7 = l15 & 7;
            const unsigned short* hr = H1s + row*128;
            short8 hf0 = *(const short8*)&hr[(( q     ^ s7) << 3)];
            short8 hf1 = *(const short8*)&hr[((( 4|q) ^ s7) << 3)];
            short8 hf2 = *(const short8*)&hr[((( 8|q) ^ s7) << 3)];
            short8 hf3 = *(const short8*)&hr[(((12|q) ^ s7) << 3)];
            #pragma unroll
            for (int mtl = 0; mtl < 2; mtl++) {
                floatx4 acc = {b2v[mtl][0], b2v[mtl][1], b2v[mtl][2], b2v[mtl][3]};
                acc = __builtin_amdgcn_mfma_f32_16x16x32_bf16(w2f[mtl][0], hf0, acc, 0, 0, 0);
                acc = __builtin_amdgcn_mfma_f32_16x16x32_bf16(w2f[mtl][1], hf1, acc, 0, 0, 0);
                acc = __builtin_amdgcn_mfma_f32_16x16x32_bf16(w2f[mtl][2], hf2, acc, 0, 0, 0);
                acc = __builtin_amdgcn_mfma_f32_16x16x32_bf16(w2f[mtl][3], hf3, acc, 0, 0, 0);
                int chnk = (((2*wv + mtl)*2 + (q>>1)) ^ s7);
                *(uint2*)&H2s[row*128 + (chnk<<3) + ((q&1)<<2)] =
                    make_uint2(pkbf(fmaxf(acc[0],0.f), fmaxf(acc[1],0.f)),
                               pkbf(fmaxf(acc[2],0.f), fmaxf(acc[3],0.f)));
            }
        }
        __syncthreads();   // H1-hi reads done; B' region reusable

        // ===== GEMM2lo: rows 0..63 [rd A', wr B' = dead H1hi] ===========
        #pragma unroll
        for (int nt = 0; nt < 4; nt++) {
            int row = nt*16 + l15;
            int s7 = l15 & 7;
            const unsigned short* hr = H1s + row*128;
            short8 hf0 = *(const short8*)&hr[(( q     ^ s7) << 3)];
            short8 hf1 = *(const short8*)&hr[((( 4|q) ^ s7) << 3)];
            short8 hf2 = *(const short8*)&hr[((( 8|q) ^ s7) << 3)];
            short8 hf3 = *(const short8*)&hr[(((12|q) ^ s7) << 3)];
            #pragma unroll
            for (int mtl = 0; mtl < 2; mtl++) {
                floatx4 acc = {b2v[mtl][0], b2v[mtl][1], b2v[mtl][2], b2v[mtl][3]};
                acc = __builtin_amdgcn_mfma_f32_16x16x32_bf16(w2f[mtl][0], hf0, acc, 0, 0, 0);
                acc = __builtin_amdgcn_mfma_f32_16x16x32_bf16(w2f[mtl][1], hf1, acc, 0, 0, 0);
                acc = __builtin_amdgcn_mfma_f32_16x16x32_bf16(w2f[mtl][2], hf2, acc, 0, 0, 0);
                acc = __builtin_amdgcn_mfma_f32_16x16x32_bf16(w2f[mtl][3], hf3, acc, 0, 0, 0);
                int chnk = (((2*wv + mtl)*2 + (q>>1)) ^ s7);
                *(uint2*)&H2s[row*128 + (chnk<<3) + ((q&1)<<2)] =
                    make_uint2(pkbf(fmaxf(acc[0],0.f), fmaxf(acc[1],0.f)),
                               pkbf(fmaxf(acc[2],0.f), fmaxf(acc[3],0.f)));
            }
        }
        __syncthreads();   // A' (H1-lo + topk scratch region) now truly dead

        // ===== G3 phase: zero scratch for next tile + GEMM3 + epilogue ===
        // (zeroing here is safe: all A' readers done; fenced from next
        //  pass1's atomics by the loop-end barrier)
        hist[tid] = 0u; hist[tid + 256] = 0u;
        if (tid < 2) { oPos[tid] = 0; cCnt[tid] = 0; fCnt[tid] = 0; }

        float esum = 0.f;
        #pragma unroll
        for (int ntl = 0; ntl < 2; ntl++) {
            int nt = 2*wv + ntl;
            int row = nt*16 + l15;
            int s7 = l15 & 7;
            const unsigned short* hr = H2s + row*128;
            floatx4 a3 = {b3C[0], b3C[1], b3C[2], b3C[3]};
            #pragma unroll
            for (int kt = 0; kt < 4; kt++) {
                short8 hf = *(const short8*)&hr[((((kt<<2)|q) ^ s7) << 3)];
                a3 = __builtin_amdgcn_mfma_f32_16x16x32_bf16(w3f[kt], hf, a3, 0, 0, 0);
            }
            // pair p = 32wv+16ntl+l15; its r lives in lane 32ntl+2*l15
            float rr = __shfl(rloc, (ntl<<5) + 2*l15, 64);
            if (rr < 12.0f) {
                float att = 0.f;
                #pragma unroll
                for (int d = 0; d < 4; d++) {
                    if (q*4 + d < MRBF) {
                        float x = a3[d];
                        float sp = fmaxf(x, 0.f) + __logf(1.f + __expf(-fabsf(x)));
                        float df = rr - cen[d];
                        att += sp * __expf(-df*df*i2w[d]);
                    }
                }
                att += __shfl_xor(att, 16, 64);
                att += __shfl_xor(att, 32, 64);
                float tt = fminf(fmaxf((rr - 10.f)*0.5f, 0.f), 1.f);
                float sw = 1.f - tt*tt*(3.f - 2.f*tt);
                esum -= att * sw;   // 4x quad-replicated; x0.25 at flush
            }
        }
        #pragma unroll
        for (int off = 1; off < 64; off <<= 1)
            esum += __shfl_xor(esum, off, 64);
        if (lane == 0) atomicAdd(&bacc[b], esum * 0.25f);
        __syncthreads();   // zeroing + H2 reads done before next pass1
    }
    if (tid < BATCH) atomicAdd(&out[tid], bacc[tid]);
}

// ---------------------------------------------------------------------------
extern "C" void kernel_launch(void* const* d_in, const int* in_sizes, int n_in,
                              void* d_out, int out_size, void* d_ws, size_t ws_size,
                              hipStream_t stream) {
    const float* R       = (const float*)d_in[0];
    const int*   seq     = (const int*)  d_in[1];
    const float* emb     = (const float*)d_in[2];
    const float* W1      = (const float*)d_in[3];
    const float* b1      = (const float*)d_in[4];
    const float* W2      = (const float*)d_in[5];
    const float* b2      = (const float*)d_in[6];
    const float* W3      = (const float*)d_in[7];
    const float* b3      = (const float*)d_in[8];
    const float* centers = (const float*)d_in[9];
    const float* widths  = (const float*)d_in[10];
    float* out = (float*)d_out;

    hipMemsetAsync(d_out, 0, out_size * sizeof(float), stream);

    fused_kernel<<<NBLOCKS, 256, 0, stream>>>(R, seq, emb, W1, b1, W2, b2, W3, b3,
                                              centers, widths, out);
}